// Round 1
// baseline (4386.241 us; speedup 1.0000x reference)
//
#include <hip/hip_runtime.h>
#include <stdint.h>

// ============================================================================
// LSTM stack, batch-sliced: reference returns out[:, -1] == batch element 255
// only, and LSTM recurrence is per-batch independent -> compute a single
// sequence (T=512) through 4 layers (H=256) + final linear.
//
// Round 0: layer-by-layer, sync-free.
//   pack_whh   : whh f32 -> packed fp16 pairs (for v_dot2_f32_f16)
//   proj_gemm  : xg[t,r] = sum_k in[t,k]*wih[r,k] + bih[r] + bhh[r]  (parallel)
//   lstm_scan  : 1 WG x 512 thr, 512 sequential steps; whh resident in
//                196 VGPRs/thread + 120KB LDS; h double-buffered fp16 in LDS
//   final_gemm : out[t,j] = sum_k h3[t,k]*lr_w[j,k] + lr_b[j]
// ============================================================================

typedef _Float16 half2v __attribute__((ext_vector_type(2)));

__device__ __forceinline__ float fdot2u(uint32_t w, uint32_t h, float acc) {
#if __has_builtin(__builtin_amdgcn_fdot2)
  return __builtin_amdgcn_fdot2(__builtin_bit_cast(half2v, w),
                                __builtin_bit_cast(half2v, h), acc, false);
#else
  half2v wv = __builtin_bit_cast(half2v, w);
  half2v hv = __builtin_bit_cast(half2v, h);
  acc += (float)wv[0] * (float)hv[0];
  acc += (float)wv[1] * (float)hv[1];
  return acc;
#endif
}

__device__ __forceinline__ float sigmoidf_(float x) {
  return 1.f / (1.f + __expf(-x));
}
__device__ __forceinline__ float tanhf_(float x) {
  // 1 - 2/(exp(2x)+1); exp overflow -> inf -> returns 1 correctly.
  return 1.f - 2.f / (__expf(2.f * x) + 1.f);
}

// ---- pack whh (1024x256 f32) into u32 of 2xfp16: wpk[r*128 + k2] = (w[r][2k2+1]<<16)|w[r][2k2]
__global__ __launch_bounds__(256) void pack_whh(const float* __restrict__ whh,
                                                uint32_t* __restrict__ wpk) {
  int idx = blockIdx.x * 256 + threadIdx.x;  // 0 .. 131071
  int r = idx >> 7, k2 = idx & 127;
  float f0 = whh[r * 256 + 2 * k2];
  float f1 = whh[r * 256 + 2 * k2 + 1];
  union { _Float16 h; uint16_t u; } a, b;
  a.h = (_Float16)f0;
  b.h = (_Float16)f1;
  wpk[idx] = (uint32_t)a.u | ((uint32_t)b.u << 16);
}

// ---- input projection: xg[t][r] = dot(in[t,:K], W[r,:K]) + bih[r] + bhh[r]
// grid (4, 64), block 256.  r = bx*256+tid, t-block of 8.
__global__ __launch_bounds__(256) void proj_gemm(const float* __restrict__ in, int istride, int K,
                                                 const float* __restrict__ W,
                                                 const float* __restrict__ bih,
                                                 const float* __restrict__ bhh,
                                                 float* __restrict__ xg) {
  __shared__ float xs[8][512];
  const int tid = threadIdx.x;
  const int r = blockIdx.x * 256 + tid;
  const int t0 = blockIdx.y * 8;
  for (int tt = 0; tt < 8; ++tt)
    for (int k = tid; k < K; k += 256)
      xs[tt][k] = in[(size_t)(t0 + tt) * istride + k];
  __syncthreads();
  float bias = bih[r] + bhh[r];
  float acc[8];
#pragma unroll
  for (int j = 0; j < 8; ++j) acc[j] = bias;
  const float* wr = W + (size_t)r * K;
  for (int k = 0; k < K; k += 4) {
    float4 w4 = *reinterpret_cast<const float4*>(wr + k);
#pragma unroll
    for (int j = 0; j < 8; ++j)
      acc[j] += xs[j][k] * w4.x + xs[j][k + 1] * w4.y + xs[j][k + 2] * w4.z +
                xs[j][k + 3] * w4.w;
  }
#pragma unroll
  for (int j = 0; j < 8; ++j) xg[(size_t)(t0 + j) * 1024 + r] = acc[j];
}

// ---- sequential scan for one layer. 1 block x 512 threads.
// thread tid owns gate rows rA=tid (i/f) and rB=tid+512 (g/o).
// weights: k2 0..97 in VGPRs (98 u32 per row), k2 98..127 in LDS transposed.
__global__ __launch_bounds__(512, 1) void lstm_scan(const uint32_t* __restrict__ wpk,  // [1024][128]
                                                    const float* __restrict__ xg,      // [512][1024]
                                                    float* __restrict__ hseq) {        // [512][256]
  __shared__ uint2 wldsT[15][1024];                // 120 KB, [j][r] = w u32 (98+2j, 99+2j)
  __shared__ __align__(16) uint16_t hbuf[2][256];  // fp16 h, ping-pong
  __shared__ float gfo[2][256];                    // f / o pre-activations
  const int tid = threadIdx.x;
  const int rA = tid, rB = tid + 512;

  // register-resident weights
  uint32_t wA[98], wB[98];
#pragma unroll
  for (int j = 0; j < 98; ++j) wA[j] = wpk[rA * 128 + j];
#pragma unroll
  for (int j = 0; j < 98; ++j) wB[j] = wpk[rB * 128 + j];

  // LDS-resident weight tail, transposed (stride-1 across lanes -> conflict-free)
  for (int rr = tid; rr < 1024; rr += 512) {
#pragma unroll
    for (int j = 0; j < 15; ++j) {
      uint2 v;
      v.x = wpk[rr * 128 + 98 + 2 * j];
      v.y = wpk[rr * 128 + 99 + 2 * j];
      wldsT[j][rr] = v;
    }
  }
  if (tid < 256) hbuf[0][tid] = 0;  // h0 = 0
  __syncthreads();

  float c = 0.f;
  int pp = 0;
  for (int t = 0; t < 512; ++t) {
    float accA0 = xg[t * 1024 + rA];  // xg already includes both biases
    float accB0 = xg[t * 1024 + rB];
    float accA1 = 0.f, accB1 = 0.f;
    const uint4* hv4 = reinterpret_cast<const uint4*>(&hbuf[pp][0]);
#pragma unroll
    for (int ch = 0; ch < 24; ++ch) {
      uint4 h4 = hv4[ch];
      accA0 = fdot2u(wA[4 * ch + 0], h4.x, accA0);
      accA1 = fdot2u(wA[4 * ch + 1], h4.y, accA1);
      accA0 = fdot2u(wA[4 * ch + 2], h4.z, accA0);
      accA1 = fdot2u(wA[4 * ch + 3], h4.w, accA1);
      accB0 = fdot2u(wB[4 * ch + 0], h4.x, accB0);
      accB1 = fdot2u(wB[4 * ch + 1], h4.y, accB1);
      accB0 = fdot2u(wB[4 * ch + 2], h4.z, accB0);
      accB1 = fdot2u(wB[4 * ch + 3], h4.w, accB1);
    }
    {  // reg tail: u32 96, 97
      uint2 h2 = *reinterpret_cast<const uint2*>(&hbuf[pp][192]);
      accA0 = fdot2u(wA[96], h2.x, accA0);
      accA1 = fdot2u(wA[97], h2.y, accA1);
      accB0 = fdot2u(wB[96], h2.x, accB0);
      accB1 = fdot2u(wB[97], h2.y, accB1);
    }
    const uint2* hv2 = reinterpret_cast<const uint2*>(&hbuf[pp][0]);
#pragma unroll
    for (int j = 0; j < 15; ++j) {  // LDS weight tail: u32 98+2j, 99+2j
      uint2 wa = wldsT[j][rA];
      uint2 wb = wldsT[j][rB];
      uint2 h2 = hv2[49 + j];
      accA0 = fdot2u(wa.x, h2.x, accA0);
      accA1 = fdot2u(wa.y, h2.y, accA1);
      accB0 = fdot2u(wb.x, h2.x, accB0);
      accB1 = fdot2u(wb.y, h2.y, accB1);
    }
    float accA = accA0 + accA1;
    float accB = accB0 + accB1;
    // exchange f/o pre-acts from threads 256..511 to 0..255
    if (tid >= 256) {
      gfo[0][tid - 256] = accA;
      gfo[1][tid - 256] = accB;
    }
    __syncthreads();
    if (tid < 256) {
      float gi = sigmoidf_(accA);        // row tid        : input gate
      float gg = tanhf_(accB);           // row tid+512    : cell candidate
      float gf = sigmoidf_(gfo[0][tid]); // row tid+256    : forget gate
      float go = sigmoidf_(gfo[1][tid]); // row tid+768    : output gate
      c = gf * c + gi * gg;
      float h = go * tanhf_(c);
      hseq[t * 256 + tid] = h;
      union { _Float16 hf; uint16_t u; } cv;
      cv.hf = (_Float16)h;
      hbuf[pp ^ 1][tid] = cv.u;
    }
    __syncthreads();
    pp ^= 1;
  }
}

// ---- final linear: out[t][j] = dot(h3[t,:], lr_w[j,:]) + lr_b[j]. grid 64, block 256.
__global__ __launch_bounds__(256) void final_gemm(const float* __restrict__ h3,
                                                  const float* __restrict__ lrw,
                                                  const float* __restrict__ lrb,
                                                  float* __restrict__ out) {
  __shared__ float xs[8][256];
  const int j = threadIdx.x;
  const int t0 = blockIdx.x * 8;
  for (int tt = 0; tt < 8; ++tt) xs[tt][j] = h3[(t0 + tt) * 256 + j];
  __syncthreads();
  float bias = lrb[j];
  float acc[8];
#pragma unroll
  for (int jj = 0; jj < 8; ++jj) acc[jj] = bias;
  const float* wr = lrw + j * 256;
  for (int k = 0; k < 256; k += 4) {
    float4 w4 = *reinterpret_cast<const float4*>(wr + k);
#pragma unroll
    for (int jj = 0; jj < 8; ++jj)
      acc[jj] += xs[jj][k] * w4.x + xs[jj][k + 1] * w4.y + xs[jj][k + 2] * w4.z +
                 xs[jj][k + 3] * w4.w;
  }
#pragma unroll
  for (int jj = 0; jj < 8; ++jj) out[(t0 + jj) * 256 + j] = acc[jj];
}

extern "C" void kernel_launch(void* const* d_in, const int* in_sizes, int n_in,
                              void* d_out, int out_size, void* d_ws, size_t ws_size,
                              hipStream_t stream) {
  (void)in_sizes; (void)n_in; (void)out_size; (void)ws_size;
  const float* x = (const float*)d_in[0];
  const float* wih[4] = {(const float*)d_in[1], (const float*)d_in[5],
                         (const float*)d_in[9], (const float*)d_in[13]};
  const float* whh[4] = {(const float*)d_in[2], (const float*)d_in[6],
                         (const float*)d_in[10], (const float*)d_in[14]};
  const float* bih[4] = {(const float*)d_in[3], (const float*)d_in[7],
                         (const float*)d_in[11], (const float*)d_in[15]};
  const float* bhh[4] = {(const float*)d_in[4], (const float*)d_in[8],
                         (const float*)d_in[12], (const float*)d_in[16]};
  const float* lrw = (const float*)d_in[17];
  const float* lrb = (const float*)d_in[18];
  float* out = (float*)d_out;

  // workspace layout (floats): xg[524288] | hA[131072] | hB[131072] | wpk (u32)[4*131072]
  float* ws = (float*)d_ws;
  float* xg = ws;
  float* hA = ws + 524288;
  float* hB = hA + 131072;
  uint32_t* wpk = (uint32_t*)(hB + 131072);

  for (int l = 0; l < 4; ++l)
    pack_whh<<<512, 256, 0, stream>>>(whh[l], wpk + (size_t)l * 131072);

  // batch element 255 only: x[t, 255, :] -> base x + 255*512, row stride B*I
  const float* in = x + 255 * 512;
  int istride = 256 * 512;
  int K = 512;
  float* hs[4] = {hA, hB, hA, hB};
  for (int l = 0; l < 4; ++l) {
    proj_gemm<<<dim3(4, 64), 256, 0, stream>>>(in, istride, K, wih[l], bih[l], bhh[l], xg);
    lstm_scan<<<1, 512, 0, stream>>>(wpk + (size_t)l * 131072, xg, hs[l]);
    in = hs[l];
    istride = 256;
    K = 256;
  }
  final_gemm<<<64, 256, 0, stream>>>(hs[3], lrw, lrb, out);
}

// Round 2
// 3498.460 us; speedup vs baseline: 1.2538x; 1.2538x over previous
//
#include <hip/hip_runtime.h>
#include <stdint.h>

// ============================================================================
// LSTM stack, batch-sliced: reference returns out[:, -1] == batch element 255
// only -> single sequence (T=512) through 4 layers (H=256) + final linear.
//
// Round 1: single-CU scan, latency fixes.
//   - xg[t+1] register-prefetched during step t (global load off critical path)
//   - pair ownership: thread 2j owns gate rows (i:j, f:j+256); thread 2j+1
//     owns (g:j+512, o:j+768); exchange via __shfl_xor(1) -> ONE barrier/step
//   - weights: 96 u32/row in arch VGPRs (launch_bounds(512,2) -> 256-reg cap),
//     32 u32/row in LDS packed [chunk][row01][tid] (conflict-free b128 reads)
// ============================================================================

typedef _Float16 half2v __attribute__((ext_vector_type(2)));

__device__ __forceinline__ float fdot2u(uint32_t w, uint32_t h, float acc) {
#if __has_builtin(__builtin_amdgcn_fdot2)
  return __builtin_amdgcn_fdot2(__builtin_bit_cast(half2v, w),
                                __builtin_bit_cast(half2v, h), acc, false);
#else
  half2v wv = __builtin_bit_cast(half2v, w);
  half2v hv = __builtin_bit_cast(half2v, h);
  acc += (float)wv[0] * (float)hv[0];
  acc += (float)wv[1] * (float)hv[1];
  return acc;
#endif
}

__device__ __forceinline__ float sigmoidf_(float x) {
  return 1.f / (1.f + __expf(-x));
}
__device__ __forceinline__ float tanhf_(float x) {
  return 1.f - 2.f / (__expf(2.f * x) + 1.f);  // exp overflow -> returns 1
}

// ---- pack whh (1024x256 f32) into u32 of 2xfp16: wpk[r*128+k2] = (w[r][2k2+1]<<16)|w[r][2k2]
__global__ __launch_bounds__(256) void pack_whh(const float* __restrict__ whh,
                                                uint32_t* __restrict__ wpk) {
  int idx = blockIdx.x * 256 + threadIdx.x;  // 0 .. 131071
  int r = idx >> 7, k2 = idx & 127;
  float f0 = whh[r * 256 + 2 * k2];
  float f1 = whh[r * 256 + 2 * k2 + 1];
  union { _Float16 h; uint16_t u; } a, b;
  a.h = (_Float16)f0;
  b.h = (_Float16)f1;
  wpk[idx] = (uint32_t)a.u | ((uint32_t)b.u << 16);
}

// ---- input projection: xg[t][r] = dot(in[t,:K], W[r,:K]) + bih[r] + bhh[r]
__global__ __launch_bounds__(256) void proj_gemm(const float* __restrict__ in, int istride, int K,
                                                 const float* __restrict__ W,
                                                 const float* __restrict__ bih,
                                                 const float* __restrict__ bhh,
                                                 float* __restrict__ xg) {
  __shared__ float xs[8][512];
  const int tid = threadIdx.x;
  const int r = blockIdx.x * 256 + tid;
  const int t0 = blockIdx.y * 8;
  for (int tt = 0; tt < 8; ++tt)
    for (int k = tid; k < K; k += 256)
      xs[tt][k] = in[(size_t)(t0 + tt) * istride + k];
  __syncthreads();
  float bias = bih[r] + bhh[r];
  float acc[8];
#pragma unroll
  for (int j = 0; j < 8; ++j) acc[j] = bias;
  const float* wr = W + (size_t)r * K;
  for (int k = 0; k < K; k += 4) {
    float4 w4 = *reinterpret_cast<const float4*>(wr + k);
#pragma unroll
    for (int j = 0; j < 8; ++j)
      acc[j] += xs[j][k] * w4.x + xs[j][k + 1] * w4.y + xs[j][k + 2] * w4.z +
                xs[j][k + 3] * w4.w;
  }
#pragma unroll
  for (int j = 0; j < 8; ++j) xg[(size_t)(t0 + j) * 1024 + r] = acc[j];
}

// ---- sequential scan for one layer. 1 block x 512 threads (8 waves, 2/SIMD).
// thread 2j:   rows rA=j     (gate i), rB=j+256 (gate f)
// thread 2j+1: rows rA=j+512 (gate g), rB=j+768 (gate o)
// weights: k2 0..95 in VGPRs (96 u32/row), k2 96..127 in LDS [c][r01][tid].
__global__ __launch_bounds__(512, 2) void lstm_scan(const uint32_t* __restrict__ wpk,  // [1024][128]
                                                    const float* __restrict__ xg,      // [512][1024]
                                                    float* __restrict__ hseq) {        // [512][256]
  __shared__ __align__(16) uint4 wlds[8 * 2 * 512];   // 128 KB: [c][r01][tid]
  __shared__ __align__(16) uint16_t hbuf[2][256];     // fp16 h, ping-pong
  const int tid = threadIdx.x;
  const int j = tid >> 1;
  const int odd = tid & 1;
  const int rA = j + (odd ? 512 : 0);
  const int rB = rA + 256;

  // register-resident weights (k2 0..95), loaded as uint4
  uint32_t wA[96], wB[96];
  {
    const uint4* gA = reinterpret_cast<const uint4*>(wpk + rA * 128);
    const uint4* gB = reinterpret_cast<const uint4*>(wpk + rB * 128);
#pragma unroll
    for (int q = 0; q < 24; ++q) {
      uint4 a = gA[q];
      wA[4 * q + 0] = a.x; wA[4 * q + 1] = a.y; wA[4 * q + 2] = a.z; wA[4 * q + 3] = a.w;
      uint4 b = gB[q];
      wB[4 * q + 0] = b.x; wB[4 * q + 1] = b.y; wB[4 * q + 2] = b.z; wB[4 * q + 3] = b.w;
    }
    // LDS weight tail (k2 96..127), per-thread slots, lane-consecutive reads
#pragma unroll
    for (int c = 0; c < 8; ++c) {
      wlds[(c * 2 + 0) * 512 + tid] = gA[24 + c];
      wlds[(c * 2 + 1) * 512 + tid] = gB[24 + c];
    }
  }
  if (tid < 256) hbuf[0][tid] = 0;  // h0 = 0
  __syncthreads();

  float c_ = 0.f;
  float xga = xg[rA], xgb = xg[rB];  // t=0 preload (xg includes both biases)
  int pp = 0;
  for (int t = 0; t < 512; ++t) {
    const int tn = (t < 511) ? (t + 1) : 511;
    float nxa = xg[tn * 1024 + rA];  // prefetch t+1; first use is next iter
    float nxb = xg[tn * 1024 + rB];

    float accA0 = xga, accA1 = 0.f, accB0 = xgb, accB1 = 0.f;
    const uint4* hv4 = reinterpret_cast<const uint4*>(&hbuf[pp][0]);
#pragma unroll
    for (int ch = 0; ch < 24; ++ch) {  // h 0..191, register weights
      uint4 h4 = hv4[ch];
      accA0 = fdot2u(wA[4 * ch + 0], h4.x, accA0);
      accA1 = fdot2u(wA[4 * ch + 1], h4.y, accA1);
      accA0 = fdot2u(wA[4 * ch + 2], h4.z, accA0);
      accA1 = fdot2u(wA[4 * ch + 3], h4.w, accA1);
      accB0 = fdot2u(wB[4 * ch + 0], h4.x, accB0);
      accB1 = fdot2u(wB[4 * ch + 1], h4.y, accB1);
      accB0 = fdot2u(wB[4 * ch + 2], h4.z, accB0);
      accB1 = fdot2u(wB[4 * ch + 3], h4.w, accB1);
    }
#pragma unroll
    for (int cc = 0; cc < 8; ++cc) {  // h 192..255, LDS weights
      uint4 h4 = hv4[24 + cc];
      uint4 wa = wlds[(cc * 2 + 0) * 512 + tid];
      uint4 wb = wlds[(cc * 2 + 1) * 512 + tid];
      accA0 = fdot2u(wa.x, h4.x, accA0);
      accA1 = fdot2u(wa.y, h4.y, accA1);
      accA0 = fdot2u(wa.z, h4.z, accA0);
      accA1 = fdot2u(wa.w, h4.w, accA1);
      accB0 = fdot2u(wb.x, h4.x, accB0);
      accB1 = fdot2u(wb.y, h4.y, accB1);
      accB0 = fdot2u(wb.z, h4.z, accB0);
      accB1 = fdot2u(wb.w, h4.w, accB1);
    }
    float accA = accA0 + accA1;
    float accB = accB0 + accB1;

    // pair exchange via DPP shuffle (same wave, adjacent lanes) -- no LDS
    float o0 = __shfl_xor(accA, 1);
    float o1 = __shfl_xor(accB, 1);
    float pi = odd ? o0 : accA;   // gate i pre-act
    float pf = odd ? o1 : accB;   // gate f
    float pg = odd ? accA : o0;   // gate g
    float po = odd ? accB : o1;   // gate o

    c_ = sigmoidf_(pf) * c_ + sigmoidf_(pi) * tanhf_(pg);
    float h = sigmoidf_(po) * tanhf_(c_);
    if (!odd) {
      hseq[t * 256 + j] = h;
      union { _Float16 hf; uint16_t u; } cv;
      cv.hf = (_Float16)h;
      hbuf[pp ^ 1][j] = cv.u;
    }
    __syncthreads();  // ONE barrier/step: h[pp^1] visible; hbuf[pp] reads drained
    pp ^= 1;
    xga = nxa;
    xgb = nxb;
  }
}

// ---- final linear: out[t][j] = dot(h3[t,:], lr_w[j,:]) + lr_b[j]
__global__ __launch_bounds__(256) void final_gemm(const float* __restrict__ h3,
                                                  const float* __restrict__ lrw,
                                                  const float* __restrict__ lrb,
                                                  float* __restrict__ out) {
  __shared__ float xs[8][256];
  const int j = threadIdx.x;
  const int t0 = blockIdx.x * 8;
  for (int tt = 0; tt < 8; ++tt) xs[tt][j] = h3[(t0 + tt) * 256 + j];
  __syncthreads();
  float bias = lrb[j];
  float acc[8];
#pragma unroll
  for (int jj = 0; jj < 8; ++jj) acc[jj] = bias;
  const float* wr = lrw + j * 256;
  for (int k = 0; k < 256; k += 4) {
    float4 w4 = *reinterpret_cast<const float4*>(wr + k);
#pragma unroll
    for (int jj = 0; jj < 8; ++jj)
      acc[jj] += xs[jj][k] * w4.x + xs[jj][k + 1] * w4.y + xs[jj][k + 2] * w4.z +
                 xs[jj][k + 3] * w4.w;
  }
#pragma unroll
  for (int jj = 0; jj < 8; ++jj) out[(t0 + jj) * 256 + j] = acc[jj];
}

extern "C" void kernel_launch(void* const* d_in, const int* in_sizes, int n_in,
                              void* d_out, int out_size, void* d_ws, size_t ws_size,
                              hipStream_t stream) {
  (void)in_sizes; (void)n_in; (void)out_size; (void)ws_size;
  const float* x = (const float*)d_in[0];
  const float* wih[4] = {(const float*)d_in[1], (const float*)d_in[5],
                         (const float*)d_in[9], (const float*)d_in[13]};
  const float* whh[4] = {(const float*)d_in[2], (const float*)d_in[6],
                         (const float*)d_in[10], (const float*)d_in[14]};
  const float* bih[4] = {(const float*)d_in[3], (const float*)d_in[7],
                         (const float*)d_in[11], (const float*)d_in[15]};
  const float* bhh[4] = {(const float*)d_in[4], (const float*)d_in[8],
                         (const float*)d_in[12], (const float*)d_in[16]};
  const float* lrw = (const float*)d_in[17];
  const float* lrb = (const float*)d_in[18];
  float* out = (float*)d_out;

  // workspace (floats): xg[524288] | hA[131072] | hB[131072] | wpk (u32)[4*131072]
  float* ws = (float*)d_ws;
  float* xg = ws;
  float* hA = ws + 524288;
  float* hB = hA + 131072;
  uint32_t* wpk = (uint32_t*)(hB + 131072);

  for (int l = 0; l < 4; ++l)
    pack_whh<<<512, 256, 0, stream>>>(whh[l], wpk + (size_t)l * 131072);

  // batch element 255 only: x[t, 255, :]
  const float* in = x + 255 * 512;
  int istride = 256 * 512;
  int K = 512;
  float* hs[4] = {hA, hB, hA, hB};
  for (int l = 0; l < 4; ++l) {
    proj_gemm<<<dim3(4, 64), 256, 0, stream>>>(in, istride, K, wih[l], bih[l], bhh[l], xg);
    lstm_scan<<<1, 512, 0, stream>>>(wpk + (size_t)l * 131072, xg, hs[l]);
    in = hs[l];
    istride = 256;
    K = 256;
  }
  final_gemm<<<64, 256, 0, stream>>>(hs[3], lrw, lrb, out);
}

// Round 3
// 1306.817 us; speedup vs baseline: 3.3564x; 2.6771x over previous
//
#include <hip/hip_runtime.h>
#include <stdint.h>

// ============================================================================
// LSTM stack, batch-sliced: reference returns out[:, -1] == batch element 255
// only -> single sequence (T=512) through 4 layers (H=256) + final linear.
//
// Round 3: cross-CU layer pipeline.
//   grid of 10 WGs (one kernel):
//     WG0: scan layer0 (xg precomputed from x by proj_gemm)
//     per layer l=1..3: 2 proj WGs (each 512 gate rows, weights in regs,
//       consume h_{l-1} stream -> produce xg_l stream) + 1 scan WG
//   sync: device-scope release/acquire counters in d_ws (forward-only DAG,
//   10 WGs co-resident on 256 CUs -> deadlock-free).
//   Scan inner loop identical to round 2 (844us/layer proven).
// ============================================================================

typedef _Float16 half2v __attribute__((ext_vector_type(2)));

__device__ __forceinline__ float fdot2u(uint32_t w, uint32_t h, float acc) {
#if __has_builtin(__builtin_amdgcn_fdot2)
  return __builtin_amdgcn_fdot2(__builtin_bit_cast(half2v, w),
                                __builtin_bit_cast(half2v, h), acc, false);
#else
  half2v wv = __builtin_bit_cast(half2v, w);
  half2v hv = __builtin_bit_cast(half2v, h);
  acc += (float)wv[0] * (float)hv[0];
  acc += (float)wv[1] * (float)hv[1];
  return acc;
#endif
}

__device__ __forceinline__ float sigmoidf_(float x) {
  return 1.f / (1.f + __expf(-x));
}
__device__ __forceinline__ float tanhf_(float x) {
  return 1.f - 2.f / (__expf(2.f * x) + 1.f);  // exp overflow -> returns 1
}

__device__ __forceinline__ int acq_load(const int* p) {
  return __hip_atomic_load(p, __ATOMIC_ACQUIRE, __HIP_MEMORY_SCOPE_AGENT);
}
__device__ __forceinline__ void rel_store(int* p, int v) {
  __hip_atomic_store(p, v, __ATOMIC_RELEASE, __HIP_MEMORY_SCOPE_AGENT);
}
// spin until *p >= need; rdy caches the last acquired value (monotone counter,
// so a cached rdy >= need from an earlier acquire already orders the data).
__device__ __forceinline__ void wait_ge(const int* p, int need, int& rdy) {
  while (rdy < need) {
    rdy = acq_load(p);
    if (rdy < need) __builtin_amdgcn_s_sleep(2);
  }
}

__global__ void zero_cnt(int* c) {
  if (threadIdx.x < 16) c[threadIdx.x] = 0;
}

// ---- pack a 1024x256 f32 matrix into u32 of 2xfp16: out[r*128+k2]
__global__ __launch_bounds__(256) void pack_whh(const float* __restrict__ w,
                                                uint32_t* __restrict__ wpk) {
  int idx = blockIdx.x * 256 + threadIdx.x;  // 0 .. 131071
  int r = idx >> 7, k2 = idx & 127;
  float f0 = w[r * 256 + 2 * k2];
  float f1 = w[r * 256 + 2 * k2 + 1];
  union { _Float16 h; uint16_t u; } a, b;
  a.h = (_Float16)f0;
  b.h = (_Float16)f1;
  wpk[idx] = (uint32_t)a.u | ((uint32_t)b.u << 16);
}

// ---- layer-0 input projection (from x, fully parallel, f32)
__global__ __launch_bounds__(256) void proj_gemm(const float* __restrict__ in, int istride, int K,
                                                 const float* __restrict__ W,
                                                 const float* __restrict__ bih,
                                                 const float* __restrict__ bhh,
                                                 float* __restrict__ xg) {
  __shared__ float xs[8][512];
  const int tid = threadIdx.x;
  const int r = blockIdx.x * 256 + tid;
  const int t0 = blockIdx.y * 8;
  for (int tt = 0; tt < 8; ++tt)
    for (int k = tid; k < K; k += 256)
      xs[tt][k] = in[(size_t)(t0 + tt) * istride + k];
  __syncthreads();
  float bias = bih[r] + bhh[r];
  float acc[8];
#pragma unroll
  for (int j = 0; j < 8; ++j) acc[j] = bias;
  const float* wr = W + (size_t)r * K;
  for (int k = 0; k < K; k += 4) {
    float4 w4 = *reinterpret_cast<const float4*>(wr + k);
#pragma unroll
    for (int j = 0; j < 8; ++j)
      acc[j] += xs[j][k] * w4.x + xs[j][k + 1] * w4.y + xs[j][k + 2] * w4.z +
                xs[j][k + 3] * w4.w;
  }
#pragma unroll
  for (int j = 0; j < 8; ++j) xg[(size_t)(t0 + j) * 1024 + r] = acc[j];
}

// ============================ pipeline stages ===============================

// scan: 512 thr; thread 2j: rows (j, j+256); thread 2j+1: rows (j+512, j+768)
// l>0: xg comes from proj WGs (poll cnt[4+(l-1)*2+odd]); releases cnt[l].
__device__ void scan_fn(int l, const uint32_t* __restrict__ wpk,
                        const float* __restrict__ xgsrc,
                        float* __restrict__ hseq, int* __restrict__ cnt) {
  __shared__ __align__(16) uint4 wlds[8 * 2 * 512];   // 128 KB
  __shared__ __align__(16) uint16_t hbuf[2][256];
  const int tid = threadIdx.x;
  const int j = tid >> 1;
  const int odd = tid & 1;
  const int rA = j + (odd ? 512 : 0);
  const int rB = rA + 256;

  uint32_t wA[96], wB[96];
  {
    const uint4* gA = reinterpret_cast<const uint4*>(wpk + rA * 128);
    const uint4* gB = reinterpret_cast<const uint4*>(wpk + rB * 128);
#pragma unroll
    for (int q = 0; q < 24; ++q) {
      uint4 a = gA[q];
      wA[4 * q + 0] = a.x; wA[4 * q + 1] = a.y; wA[4 * q + 2] = a.z; wA[4 * q + 3] = a.w;
      uint4 b = gB[q];
      wB[4 * q + 0] = b.x; wB[4 * q + 1] = b.y; wB[4 * q + 2] = b.z; wB[4 * q + 3] = b.w;
    }
#pragma unroll
    for (int c = 0; c < 8; ++c) {
      wlds[(c * 2 + 0) * 512 + tid] = gA[24 + c];
      wlds[(c * 2 + 1) * 512 + tid] = gB[24 + c];
    }
  }
  if (tid < 256) hbuf[0][tid] = 0;
  __syncthreads();

  const int* mycnt = &cnt[4 + (l - 1) * 2 + odd];
  int rdy = 0;
  if (l) wait_ge(mycnt, 1, rdy);
  float c_ = 0.f;
  float xga = xgsrc[rA], xgb = xgsrc[rB];
  int pp = 0;
  for (int t = 0; t < 512; ++t) {
    const int tn = (t < 511) ? (t + 1) : 511;
    if (l) {
      int need = (t + 2 > 512) ? 512 : (t + 2);
      wait_ge(mycnt, need, rdy);
    }
    float nxa = xgsrc[tn * 1024 + rA];
    float nxb = xgsrc[tn * 1024 + rB];

    float accA0 = xga, accA1 = 0.f, accB0 = xgb, accB1 = 0.f;
    const uint4* hv4 = reinterpret_cast<const uint4*>(&hbuf[pp][0]);
#pragma unroll
    for (int ch = 0; ch < 24; ++ch) {
      uint4 h4 = hv4[ch];
      accA0 = fdot2u(wA[4 * ch + 0], h4.x, accA0);
      accA1 = fdot2u(wA[4 * ch + 1], h4.y, accA1);
      accA0 = fdot2u(wA[4 * ch + 2], h4.z, accA0);
      accA1 = fdot2u(wA[4 * ch + 3], h4.w, accA1);
      accB0 = fdot2u(wB[4 * ch + 0], h4.x, accB0);
      accB1 = fdot2u(wB[4 * ch + 1], h4.y, accB1);
      accB0 = fdot2u(wB[4 * ch + 2], h4.z, accB0);
      accB1 = fdot2u(wB[4 * ch + 3], h4.w, accB1);
    }
#pragma unroll
    for (int cc = 0; cc < 8; ++cc) {
      uint4 h4 = hv4[24 + cc];
      uint4 wa = wlds[(cc * 2 + 0) * 512 + tid];
      uint4 wb = wlds[(cc * 2 + 1) * 512 + tid];
      accA0 = fdot2u(wa.x, h4.x, accA0);
      accA1 = fdot2u(wa.y, h4.y, accA1);
      accA0 = fdot2u(wa.z, h4.z, accA0);
      accA1 = fdot2u(wa.w, h4.w, accA1);
      accB0 = fdot2u(wb.x, h4.x, accB0);
      accB1 = fdot2u(wb.y, h4.y, accB1);
      accB0 = fdot2u(wb.z, h4.z, accB0);
      accB1 = fdot2u(wb.w, h4.w, accB1);
    }
    float accA = accA0 + accA1;
    float accB = accB0 + accB1;

    float o0 = __shfl_xor(accA, 1);
    float o1 = __shfl_xor(accB, 1);
    float pi = odd ? o0 : accA;
    float pf = odd ? o1 : accB;
    float pg = odd ? accA : o0;
    float po = odd ? accB : o1;

    c_ = sigmoidf_(pf) * c_ + sigmoidf_(pi) * tanhf_(pg);
    float h = sigmoidf_(po) * tanhf_(c_);
    if (!odd) {
      hseq[t * 256 + j] = h;
      union { _Float16 hf; uint16_t u; } cv;
      cv.hf = (_Float16)h;
      hbuf[pp ^ 1][j] = cv.u;
    }
    __syncthreads();  // hbuf[pp^1] visible; vmcnt drained (h stores complete)
    if (tid == 0) rel_store(&cnt[l], t + 1);
    pp ^= 1;
    xga = nxa;
    xgb = nxb;
  }
}

// proj: 512 thr, WG owns rows [half*512, half*512+512). 1 row/thread, weights
// fully register-resident. Polls cnt[l-1] (scan of layer l-1), releases
// cnt[4+(l-1)*2+half].
__device__ void proj_fn(int l, int half, const uint32_t* __restrict__ wpk,
                        const float* __restrict__ bih, const float* __restrict__ bhh,
                        const float* __restrict__ hsrc,   // hseq layer l-1 (f32)
                        float* __restrict__ xgdst, int* __restrict__ cnt) {
  __shared__ __align__(16) uint32_t hpk[128];  // h as packed fp16 pairs
  const int tid = threadIdx.x;
  const int row = half * 512 + tid;

  uint32_t wr_[128];
  {
    const uint4* g = reinterpret_cast<const uint4*>(wpk + (size_t)row * 128);
#pragma unroll
    for (int q = 0; q < 32; ++q) {
      uint4 v = g[q];
      wr_[4 * q + 0] = v.x; wr_[4 * q + 1] = v.y; wr_[4 * q + 2] = v.z; wr_[4 * q + 3] = v.w;
    }
  }
  const float bias = bih[row] + bhh[row];
  const int* prev = &cnt[l - 1];
  int* mine = &cnt[4 + (l - 1) * 2 + half];
  int rdy = 0;

  for (int t = 0; t < 512; ++t) {
    wait_ge(prev, t + 1, rdy);
    if (tid < 128) {
      float2 hv = *reinterpret_cast<const float2*>(hsrc + t * 256 + 2 * tid);
      union { _Float16 h; uint16_t u; } a, b;
      a.h = (_Float16)hv.x;
      b.h = (_Float16)hv.y;
      hpk[tid] = (uint32_t)a.u | ((uint32_t)b.u << 16);
    }
    __syncthreads();  // h staged
    float a0 = bias, a1 = 0.f;
    const uint4* hv4 = reinterpret_cast<const uint4*>(hpk);
#pragma unroll
    for (int q = 0; q < 32; ++q) {
      uint4 h4 = hv4[q];
      a0 = fdot2u(wr_[4 * q + 0], h4.x, a0);
      a1 = fdot2u(wr_[4 * q + 1], h4.y, a1);
      a0 = fdot2u(wr_[4 * q + 2], h4.z, a0);
      a1 = fdot2u(wr_[4 * q + 3], h4.w, a1);
    }
    xgdst[t * 1024 + row] = a0 + a1;
    __syncthreads();  // xg stores drained; hpk reads done before next overwrite
    if (tid == 0) rel_store(mine, t + 1);
  }
}

// grid.x = 10: 0=scan0 | 1,2=proj1 | 3=scan1 | 4,5=proj2 | 6=scan2 | 7,8=proj3 | 9=scan3
__global__ __launch_bounds__(512, 2) void pipeline(
    const uint32_t* __restrict__ wpkhh, const uint32_t* __restrict__ wpkih,
    const float* __restrict__ xg0, float* __restrict__ xgp,
    float* __restrict__ hseq,
    const float* __restrict__ bih1, const float* __restrict__ bhh1,
    const float* __restrict__ bih2, const float* __restrict__ bhh2,
    const float* __restrict__ bih3, const float* __restrict__ bhh3,
    int* __restrict__ cnt) {
  const int bx = blockIdx.x;
  if (bx == 0) {
    scan_fn(0, wpkhh, xg0, hseq, cnt);
  } else {
    const int g = bx - 1;
    const int l = g / 3 + 1;
    const int r = g % 3;
    const float* bih = (l == 1) ? bih1 : (l == 2) ? bih2 : bih3;
    const float* bhh = (l == 1) ? bhh1 : (l == 2) ? bhh2 : bhh3;
    if (r < 2)
      proj_fn(l, r, wpkih + (size_t)(l - 1) * 131072, bih, bhh,
              hseq + (size_t)(l - 1) * 131072, xgp + (size_t)(l - 1) * 524288, cnt);
    else
      scan_fn(l, wpkhh + (size_t)l * 131072, xgp + (size_t)(l - 1) * 524288,
              hseq + (size_t)l * 131072, cnt);
  }
}

// ---- final linear
__global__ __launch_bounds__(256) void final_gemm(const float* __restrict__ h3,
                                                  const float* __restrict__ lrw,
                                                  const float* __restrict__ lrb,
                                                  float* __restrict__ out) {
  __shared__ float xs[8][256];
  const int j = threadIdx.x;
  const int t0 = blockIdx.x * 8;
  for (int tt = 0; tt < 8; ++tt) xs[tt][j] = h3[(t0 + tt) * 256 + j];
  __syncthreads();
  float bias = lrb[j];
  float acc[8];
#pragma unroll
  for (int jj = 0; jj < 8; ++jj) acc[jj] = bias;
  const float* wr = lrw + j * 256;
  for (int k = 0; k < 256; k += 4) {
    float4 w4 = *reinterpret_cast<const float4*>(wr + k);
#pragma unroll
    for (int jj = 0; jj < 8; ++jj)
      acc[jj] += xs[jj][k] * w4.x + xs[jj][k + 1] * w4.y + xs[jj][k + 2] * w4.z +
                 xs[jj][k + 3] * w4.w;
  }
#pragma unroll
  for (int jj = 0; jj < 8; ++jj) out[(t0 + jj) * 256 + j] = acc[jj];
}

extern "C" void kernel_launch(void* const* d_in, const int* in_sizes, int n_in,
                              void* d_out, int out_size, void* d_ws, size_t ws_size,
                              hipStream_t stream) {
  (void)in_sizes; (void)n_in; (void)out_size; (void)ws_size;
  const float* x = (const float*)d_in[0];
  const float* wih[4] = {(const float*)d_in[1], (const float*)d_in[5],
                         (const float*)d_in[9], (const float*)d_in[13]};
  const float* whh[4] = {(const float*)d_in[2], (const float*)d_in[6],
                         (const float*)d_in[10], (const float*)d_in[14]};
  const float* bih[4] = {(const float*)d_in[3], (const float*)d_in[7],
                         (const float*)d_in[11], (const float*)d_in[15]};
  const float* bhh[4] = {(const float*)d_in[4], (const float*)d_in[8],
                         (const float*)d_in[12], (const float*)d_in[16]};
  const float* lrw = (const float*)d_in[17];
  const float* lrb = (const float*)d_in[18];
  float* out = (float*)d_out;

  // ws layout (4B units):
  //   xg0[524288] | xgp[3*524288] | hseq[4*131072] | wpkhh u32[4*131072]
  //   | wpkih u32[3*131072] | cnt int[16]              (~14.2 MB total)
  float* ws = (float*)d_ws;
  float* xg0 = ws;
  float* xgp = ws + 524288;
  float* hseq = xgp + 3 * 524288;
  uint32_t* wpkhh = (uint32_t*)(hseq + 4 * 131072);
  uint32_t* wpkih = wpkhh + 4 * 131072;
  int* cnt = (int*)(wpkih + 3 * 131072);

  zero_cnt<<<1, 64, 0, stream>>>(cnt);
  for (int l = 0; l < 4; ++l)
    pack_whh<<<512, 256, 0, stream>>>(whh[l], wpkhh + (size_t)l * 131072);
  for (int l = 1; l < 4; ++l)
    pack_whh<<<512, 256, 0, stream>>>(wih[l], wpkih + (size_t)(l - 1) * 131072);

  // layer-0 projection from x (batch element 255)
  proj_gemm<<<dim3(4, 64), 256, 0, stream>>>(x + 255 * 512, 256 * 512, 512,
                                             wih[0], bih[0], bhh[0], xg0);

  pipeline<<<10, 512, 0, stream>>>(wpkhh, wpkih, xg0, xgp, hseq,
                                   bih[1], bhh[1], bih[2], bhh[2], bih[3], bhh[3],
                                   cnt);

  final_gemm<<<64, 256, 0, stream>>>(hseq + 3 * 131072, lrw, lrb, out);
}

// Round 4
// 1175.601 us; speedup vs baseline: 3.7311x; 1.1116x over previous
//
#include <hip/hip_runtime.h>
#include <stdint.h>

// ============================================================================
// LSTM stack, batch-sliced: reference returns out[:, -1] == batch element 255
// only -> single sequence (T=512) through 4 layers (H=256) + final linear.
//
// Round 4: cross-CU layer pipeline with CHEAP sync.
//   Round 3 used agent-scope acquire/release -> buffer_inv (L2 invalidate) per
//   acquire and buffer_wbl2 (L2 writeback) per release, every step, from 10
//   WGs -> cache-maintenance storm, 5790 cy/step. Now ALL cross-WG data
//   (h, xg, counters) moves via RELAXED agent atomics (= global_load/store
//   sc0 sc1, device-coherent, NO cache maintenance). Ordering: data stores ->
//   __syncthreads (per-wave vmcnt(0) drain before s_barrier) -> tid0 counter
//   store; consumer polls counter, then data loads (control-dependent).
//   Counters padded to 128B (one cacheline each).
// ============================================================================

typedef _Float16 half2v __attribute__((ext_vector_type(2)));

__device__ __forceinline__ float fdot2u(uint32_t w, uint32_t h, float acc) {
#if __has_builtin(__builtin_amdgcn_fdot2)
  return __builtin_amdgcn_fdot2(__builtin_bit_cast(half2v, w),
                                __builtin_bit_cast(half2v, h), acc, false);
#else
  half2v wv = __builtin_bit_cast(half2v, w);
  half2v hv = __builtin_bit_cast(half2v, h);
  acc += (float)wv[0] * (float)hv[0];
  acc += (float)wv[1] * (float)hv[1];
  return acc;
#endif
}

__device__ __forceinline__ float sigmoidf_(float x) {
  return 1.f / (1.f + __expf(-x));
}
__device__ __forceinline__ float tanhf_(float x) {
  return 1.f - 2.f / (__expf(2.f * x) + 1.f);  // exp overflow -> returns 1
}

#define CNT_STRIDE 32  // ints per counter slot = 128 B = 1 cacheline

__device__ __forceinline__ int cnt_load(const int* p) {
  return __hip_atomic_load(p, __ATOMIC_RELAXED, __HIP_MEMORY_SCOPE_AGENT);
}
__device__ __forceinline__ void cnt_store(int* p, int v) {
  __hip_atomic_store(p, v, __ATOMIC_RELAXED, __HIP_MEMORY_SCOPE_AGENT);
}
// device-coherent (sc0 sc1) data accesses -- no cache maintenance
__device__ __forceinline__ float ldg_f32(const float* p) {
  uint32_t u = __hip_atomic_load((const uint32_t*)p, __ATOMIC_RELAXED,
                                 __HIP_MEMORY_SCOPE_AGENT);
  return __builtin_bit_cast(float, u);
}
__device__ __forceinline__ void stg_f32(float* p, float v) {
  __hip_atomic_store((uint32_t*)p, __builtin_bit_cast(uint32_t, v),
                     __ATOMIC_RELAXED, __HIP_MEMORY_SCOPE_AGENT);
}
__device__ __forceinline__ uint64_t ldg_u64(const float* p) {
  return __hip_atomic_load((const uint64_t*)p, __ATOMIC_RELAXED,
                           __HIP_MEMORY_SCOPE_AGENT);
}

// spin until *p >= need; rdy caches the last observed value (monotone counter)
__device__ __forceinline__ void wait_ge(const int* p, int need, int& rdy) {
  while (rdy < need) {
    rdy = cnt_load(p);
    if (rdy < need) __builtin_amdgcn_s_sleep(2);
  }
  asm volatile("" ::: "memory");  // keep data loads below the poll (compiler)
}

__global__ void zero_cnt(int* c) {
  if (threadIdx.x < 16 * CNT_STRIDE) c[threadIdx.x] = 0;
}

// ---- pack a 1024x256 f32 matrix into u32 of 2xfp16: out[r*128+k2]
__global__ __launch_bounds__(256) void pack_whh(const float* __restrict__ w,
                                                uint32_t* __restrict__ wpk) {
  int idx = blockIdx.x * 256 + threadIdx.x;  // 0 .. 131071
  int r = idx >> 7, k2 = idx & 127;
  float f0 = w[r * 256 + 2 * k2];
  float f1 = w[r * 256 + 2 * k2 + 1];
  union { _Float16 h; uint16_t u; } a, b;
  a.h = (_Float16)f0;
  b.h = (_Float16)f1;
  wpk[idx] = (uint32_t)a.u | ((uint32_t)b.u << 16);
}

// ---- layer-0 input projection (from x, fully parallel, f32)
__global__ __launch_bounds__(256) void proj_gemm(const float* __restrict__ in, int istride, int K,
                                                 const float* __restrict__ W,
                                                 const float* __restrict__ bih,
                                                 const float* __restrict__ bhh,
                                                 float* __restrict__ xg) {
  __shared__ float xs[8][512];
  const int tid = threadIdx.x;
  const int r = blockIdx.x * 256 + tid;
  const int t0 = blockIdx.y * 8;
  for (int tt = 0; tt < 8; ++tt)
    for (int k = tid; k < K; k += 256)
      xs[tt][k] = in[(size_t)(t0 + tt) * istride + k];
  __syncthreads();
  float bias = bih[r] + bhh[r];
  float acc[8];
#pragma unroll
  for (int j = 0; j < 8; ++j) acc[j] = bias;
  const float* wr = W + (size_t)r * K;
  for (int k = 0; k < K; k += 4) {
    float4 w4 = *reinterpret_cast<const float4*>(wr + k);
#pragma unroll
    for (int j = 0; j < 8; ++j)
      acc[j] += xs[j][k] * w4.x + xs[j][k + 1] * w4.y + xs[j][k + 2] * w4.z +
                xs[j][k + 3] * w4.w;
  }
#pragma unroll
  for (int j = 0; j < 8; ++j) xg[(size_t)(t0 + j) * 1024 + r] = acc[j];
}

// ============================ pipeline stages ===============================

// scan: 512 thr; thread 2j: rows (j, j+256); thread 2j+1: rows (j+512, j+768)
__device__ void scan_fn(int l, const uint32_t* __restrict__ wpk,
                        const float* __restrict__ xgsrc,
                        float* __restrict__ hseq, int* __restrict__ cnt) {
  __shared__ __align__(16) uint4 wlds[8 * 2 * 512];   // 128 KB
  __shared__ __align__(16) uint16_t hbuf[2][256];
  const int tid = threadIdx.x;
  const int j = tid >> 1;
  const int odd = tid & 1;
  const int rA = j + (odd ? 512 : 0);
  const int rB = rA + 256;

  uint32_t wA[96], wB[96];
  {
    const uint4* gA = reinterpret_cast<const uint4*>(wpk + rA * 128);
    const uint4* gB = reinterpret_cast<const uint4*>(wpk + rB * 128);
#pragma unroll
    for (int q = 0; q < 24; ++q) {
      uint4 a = gA[q];
      wA[4 * q + 0] = a.x; wA[4 * q + 1] = a.y; wA[4 * q + 2] = a.z; wA[4 * q + 3] = a.w;
      uint4 b = gB[q];
      wB[4 * q + 0] = b.x; wB[4 * q + 1] = b.y; wB[4 * q + 2] = b.z; wB[4 * q + 3] = b.w;
    }
#pragma unroll
    for (int c = 0; c < 8; ++c) {
      wlds[(c * 2 + 0) * 512 + tid] = gA[24 + c];
      wlds[(c * 2 + 1) * 512 + tid] = gB[24 + c];
    }
  }
  if (tid < 256) hbuf[0][tid] = 0;
  __syncthreads();

  const int* mycnt = &cnt[(4 + (l - 1) * 2 + odd) * CNT_STRIDE];
  int rdy = 0;
  if (l) wait_ge(mycnt, 1, rdy);
  float c_ = 0.f;
  float xga = ldg_f32(xgsrc + rA), xgb = ldg_f32(xgsrc + rB);
  int pp = 0;
  for (int t = 0; t < 512; ++t) {
    const int tn = (t < 511) ? (t + 1) : 511;
    if (l) {
      int need = (t + 2 > 512) ? 512 : (t + 2);
      wait_ge(mycnt, need, rdy);
    }
    float nxa = ldg_f32(xgsrc + tn * 1024 + rA);  // prefetch t+1
    float nxb = ldg_f32(xgsrc + tn * 1024 + rB);

    float accA0 = xga, accA1 = 0.f, accB0 = xgb, accB1 = 0.f;
    const uint4* hv4 = reinterpret_cast<const uint4*>(&hbuf[pp][0]);
#pragma unroll
    for (int ch = 0; ch < 24; ++ch) {
      uint4 h4 = hv4[ch];
      accA0 = fdot2u(wA[4 * ch + 0], h4.x, accA0);
      accA1 = fdot2u(wA[4 * ch + 1], h4.y, accA1);
      accA0 = fdot2u(wA[4 * ch + 2], h4.z, accA0);
      accA1 = fdot2u(wA[4 * ch + 3], h4.w, accA1);
      accB0 = fdot2u(wB[4 * ch + 0], h4.x, accB0);
      accB1 = fdot2u(wB[4 * ch + 1], h4.y, accB1);
      accB0 = fdot2u(wB[4 * ch + 2], h4.z, accB0);
      accB1 = fdot2u(wB[4 * ch + 3], h4.w, accB1);
    }
#pragma unroll
    for (int cc = 0; cc < 8; ++cc) {
      uint4 h4 = hv4[24 + cc];
      uint4 wa = wlds[(cc * 2 + 0) * 512 + tid];
      uint4 wb = wlds[(cc * 2 + 1) * 512 + tid];
      accA0 = fdot2u(wa.x, h4.x, accA0);
      accA1 = fdot2u(wa.y, h4.y, accA1);
      accA0 = fdot2u(wa.z, h4.z, accA0);
      accA1 = fdot2u(wa.w, h4.w, accA1);
      accB0 = fdot2u(wb.x, h4.x, accB0);
      accB1 = fdot2u(wb.y, h4.y, accB1);
      accB0 = fdot2u(wb.z, h4.z, accB0);
      accB1 = fdot2u(wb.w, h4.w, accB1);
    }
    float accA = accA0 + accA1;
    float accB = accB0 + accB1;

    float o0 = __shfl_xor(accA, 1);
    float o1 = __shfl_xor(accB, 1);
    float pi = odd ? o0 : accA;
    float pf = odd ? o1 : accB;
    float pg = odd ? accA : o0;
    float po = odd ? accB : o1;

    c_ = sigmoidf_(pf) * c_ + sigmoidf_(pi) * tanhf_(pg);
    float h = sigmoidf_(po) * tanhf_(c_);
    if (!odd) {
      stg_f32(hseq + t * 256 + j, h);  // device-coherent store
      union { _Float16 hf; uint16_t u; } cv;
      cv.hf = (_Float16)h;
      hbuf[pp ^ 1][j] = cv.u;
    }
    __syncthreads();  // all waves drain vmcnt(0) -> h stores at coherence point
    if (tid == 0) cnt_store(&cnt[l * CNT_STRIDE], t + 1);
    pp ^= 1;
    xga = nxa;
    xgb = nxb;
  }
}

// proj: 512 thr, WG owns rows [half*512, half*512+512). 1 row/thread.
__device__ void proj_fn(int l, int half, const uint32_t* __restrict__ wpk,
                        const float* __restrict__ bih, const float* __restrict__ bhh,
                        const float* __restrict__ hsrc,   // hseq layer l-1 (f32)
                        float* __restrict__ xgdst, int* __restrict__ cnt) {
  __shared__ __align__(16) uint32_t hpk[128];  // h as packed fp16 pairs
  const int tid = threadIdx.x;
  const int row = half * 512 + tid;

  uint32_t wr_[128];
  {
    const uint4* g = reinterpret_cast<const uint4*>(wpk + (size_t)row * 128);
#pragma unroll
    for (int q = 0; q < 32; ++q) {
      uint4 v = g[q];
      wr_[4 * q + 0] = v.x; wr_[4 * q + 1] = v.y; wr_[4 * q + 2] = v.z; wr_[4 * q + 3] = v.w;
    }
  }
  const float bias = bih[row] + bhh[row];
  const int* prev = &cnt[(l - 1) * CNT_STRIDE];
  int* mine = &cnt[(4 + (l - 1) * 2 + half) * CNT_STRIDE];
  int rdy = 0;

  for (int t = 0; t < 512; ++t) {
    wait_ge(prev, t + 1, rdy);
    if (tid < 128) {
      uint64_t hv = ldg_u64(hsrc + t * 256 + 2 * tid);  // device-coherent 8B
      float hx = __builtin_bit_cast(float, (uint32_t)hv);
      float hy = __builtin_bit_cast(float, (uint32_t)(hv >> 32));
      union { _Float16 h; uint16_t u; } a, b;
      a.h = (_Float16)hx;
      b.h = (_Float16)hy;
      hpk[tid] = (uint32_t)a.u | ((uint32_t)b.u << 16);
    }
    __syncthreads();  // h staged
    float a0 = bias, a1 = 0.f;
    const uint4* hv4 = reinterpret_cast<const uint4*>(hpk);
#pragma unroll
    for (int q = 0; q < 32; ++q) {
      uint4 h4 = hv4[q];
      a0 = fdot2u(wr_[4 * q + 0], h4.x, a0);
      a1 = fdot2u(wr_[4 * q + 1], h4.y, a1);
      a0 = fdot2u(wr_[4 * q + 2], h4.z, a0);
      a1 = fdot2u(wr_[4 * q + 3], h4.w, a1);
    }
    stg_f32(xgdst + t * 1024 + row, a0 + a1);  // device-coherent store
    __syncthreads();  // xg stores drained; hpk reads done before next overwrite
    if (tid == 0) cnt_store(mine, t + 1);
  }
}

// grid.x = 10: 0=scan0 | 1,2=proj1 | 3=scan1 | 4,5=proj2 | 6=scan2 | 7,8=proj3 | 9=scan3
__global__ __launch_bounds__(512, 2) void pipeline(
    const uint32_t* __restrict__ wpkhh, const uint32_t* __restrict__ wpkih,
    const float* __restrict__ xg0, float* __restrict__ xgp,
    float* __restrict__ hseq,
    const float* __restrict__ bih1, const float* __restrict__ bhh1,
    const float* __restrict__ bih2, const float* __restrict__ bhh2,
    const float* __restrict__ bih3, const float* __restrict__ bhh3,
    int* __restrict__ cnt) {
  const int bx = blockIdx.x;
  if (bx == 0) {
    scan_fn(0, wpkhh, xg0, hseq, cnt);
  } else {
    const int g = bx - 1;
    const int l = g / 3 + 1;
    const int r = g % 3;
    const float* bih = (l == 1) ? bih1 : (l == 2) ? bih2 : bih3;
    const float* bhh = (l == 1) ? bhh1 : (l == 2) ? bhh2 : bhh3;
    if (r < 2)
      proj_fn(l, r, wpkih + (size_t)(l - 1) * 131072, bih, bhh,
              hseq + (size_t)(l - 1) * 131072, xgp + (size_t)(l - 1) * 524288, cnt);
    else
      scan_fn(l, wpkhh + (size_t)l * 131072, xgp + (size_t)(l - 1) * 524288,
              hseq + (size_t)l * 131072, cnt);
  }
}

// ---- final linear
__global__ __launch_bounds__(256) void final_gemm(const float* __restrict__ h3,
                                                  const float* __restrict__ lrw,
                                                  const float* __restrict__ lrb,
                                                  float* __restrict__ out) {
  __shared__ float xs[8][256];
  const int j = threadIdx.x;
  const int t0 = blockIdx.x * 8;
  for (int tt = 0; tt < 8; ++tt) xs[tt][j] = h3[(t0 + tt) * 256 + j];
  __syncthreads();
  float bias = lrb[j];
  float acc[8];
#pragma unroll
  for (int jj = 0; jj < 8; ++jj) acc[jj] = bias;
  const float* wr = lrw + j * 256;
  for (int k = 0; k < 256; k += 4) {
    float4 w4 = *reinterpret_cast<const float4*>(wr + k);
#pragma unroll
    for (int jj = 0; jj < 8; ++jj)
      acc[jj] += xs[jj][k] * w4.x + xs[jj][k + 1] * w4.y + xs[jj][k + 2] * w4.z +
                 xs[jj][k + 3] * w4.w;
  }
#pragma unroll
  for (int jj = 0; jj < 8; ++jj) out[(t0 + jj) * 256 + j] = acc[jj];
}

extern "C" void kernel_launch(void* const* d_in, const int* in_sizes, int n_in,
                              void* d_out, int out_size, void* d_ws, size_t ws_size,
                              hipStream_t stream) {
  (void)in_sizes; (void)n_in; (void)out_size; (void)ws_size;
  const float* x = (const float*)d_in[0];
  const float* wih[4] = {(const float*)d_in[1], (const float*)d_in[5],
                         (const float*)d_in[9], (const float*)d_in[13]};
  const float* whh[4] = {(const float*)d_in[2], (const float*)d_in[6],
                         (const float*)d_in[10], (const float*)d_in[14]};
  const float* bih[4] = {(const float*)d_in[3], (const float*)d_in[7],
                         (const float*)d_in[11], (const float*)d_in[15]};
  const float* bhh[4] = {(const float*)d_in[4], (const float*)d_in[8],
                         (const float*)d_in[12], (const float*)d_in[16]};
  const float* lrw = (const float*)d_in[17];
  const float* lrb = (const float*)d_in[18];
  float* out = (float*)d_out;

  // ws layout (4B units):
  //   xg0[524288] | xgp[3*524288] | hseq[4*131072] | wpkhh u32[4*131072]
  //   | wpkih u32[3*131072] | cnt int[16*CNT_STRIDE]      (~14.2 MB total)
  float* ws = (float*)d_ws;
  float* xg0 = ws;
  float* xgp = ws + 524288;
  float* hseq = xgp + 3 * 524288;
  uint32_t* wpkhh = (uint32_t*)(hseq + 4 * 131072);
  uint32_t* wpkih = wpkhh + 4 * 131072;
  int* cnt = (int*)(wpkih + 3 * 131072);

  zero_cnt<<<1, 512, 0, stream>>>(cnt);
  for (int l = 0; l < 4; ++l)
    pack_whh<<<512, 256, 0, stream>>>(whh[l], wpkhh + (size_t)l * 131072);
  for (int l = 1; l < 4; ++l)
    pack_whh<<<512, 256, 0, stream>>>(wih[l], wpkih + (size_t)(l - 1) * 131072);

  // layer-0 projection from x (batch element 255)
  proj_gemm<<<dim3(4, 64), 256, 0, stream>>>(x + 255 * 512, 256 * 512, 512,
                                             wih[0], bih[0], bhh[0], xg0);

  pipeline<<<10, 512, 0, stream>>>(wpkhh, wpkih, xg0, xgp, hseq,
                                   bih[1], bhh[1], bih[2], bhh[2], bih[3], bhh[3],
                                   cnt);

  final_gemm<<<64, 256, 0, stream>>>(hseq + 3 * 131072, lrw, lrb, out);
}